// Round 1
// baseline (344.106 us; speedup 1.0000x reference)
//
#include <hip/hip_runtime.h>
#include <math.h>

#define KD 200
#define CD 352
#define NITER 18
#define LMB 0.01f

__device__ __forceinline__ float4 ld4(const float* p) { return *(const float4*)p; }
__device__ __forceinline__ void st4(float* p, float4 v) { *(float4*)p = v; }
__device__ __forceinline__ float rdlane(float v, int lane) {
    return __int_as_float(__builtin_amdgcn_readlane(__float_as_int(v), lane));
}

// ---------------- Kernel 1: G = A A^T, R = B A^T (batched, 32x32 tiles) ----------------
// 784 blocks (vs 256): ~3 blocks/CU so one block's barriers overlap another's compute.
// 2-wave blocks, 2x4 micro-tile, register prefetch of next k-chunk between barriers.
__global__ __launch_bounds__(128) void gemm_gr_kernel(
    const float* __restrict__ A, const float* __restrict__ B,
    float* __restrict__ G, float* __restrict__ R)
{
    __shared__ __align__(16) float Ms[16][36];   // [k][m], pad to 36 (2-way max on writes)
    __shared__ __align__(16) float Ns[16][36];   // [k][n]
    const int tid = threadIdx.x;
    const int z = blockIdx.z;
    const int b = z >> 1, which = z & 1;
    const float* __restrict__ Xb = (which ? B : A) + (size_t)b * KD * CD;
    const float* __restrict__ Ab = A + (size_t)b * KD * CD;
    float* __restrict__ O = (which ? R : G) + (size_t)b * KD * KD;
    const int tileM = blockIdx.y * 32;
    const int tileN = blockIdx.x * 32;

    const int lm = tid >> 2;             // 0..31 (row within tile)
    const int kq = (tid & 3) * 4;        // 0,4,8,12
    const int rowM = min(tileM + lm, KD - 1);
    const int rowN = min(tileN + lm, KD - 1);
    const float* __restrict__ Xrow = Xb + (size_t)rowM * CD;
    const float* __restrict__ Arow = Ab + (size_t)rowN * CD;

    const int ty = tid >> 3, tx = tid & 7;   // ty 0..15, tx 0..7
    const int m0 = ty * 2, n0 = tx * 4;

    float acc[2][4] = {};
    // prefetch chunk 0 into registers
    float4 vx = ld4(Xrow + kq);
    float4 va = ld4(Arow + kq);
    for (int kk = 0; kk < CD; kk += 16) {
        __syncthreads();                 // previous chunk's LDS reads done
        Ms[kq + 0][lm] = vx.x; Ms[kq + 1][lm] = vx.y;
        Ms[kq + 2][lm] = vx.z; Ms[kq + 3][lm] = vx.w;
        Ns[kq + 0][lm] = va.x; Ns[kq + 1][lm] = va.y;
        Ns[kq + 2][lm] = va.z; Ns[kq + 3][lm] = va.w;
        if (kk + 16 < CD) {              // issue next chunk's loads; latency hides under FMAs
            vx = ld4(Xrow + kk + 16 + kq);
            va = ld4(Arow + kk + 16 + kq);
        }
        __syncthreads();                 // LDS writes visible
        #pragma unroll
        for (int k = 0; k < 16; ++k) {
            const float2 am = *(const float2*)&Ms[k][m0];
            const float4 an = ld4(&Ns[k][n0]);
            acc[0][0] = fmaf(am.x, an.x, acc[0][0]);
            acc[0][1] = fmaf(am.x, an.y, acc[0][1]);
            acc[0][2] = fmaf(am.x, an.z, acc[0][2]);
            acc[0][3] = fmaf(am.x, an.w, acc[0][3]);
            acc[1][0] = fmaf(am.y, an.x, acc[1][0]);
            acc[1][1] = fmaf(am.y, an.y, acc[1][1]);
            acc[1][2] = fmaf(am.y, an.z, acc[1][2]);
            acc[1][3] = fmaf(am.y, an.w, acc[1][3]);
        }
    }
    const int gn = tileN + n0;
    if (gn < KD) {
        #pragma unroll
        for (int i = 0; i < 2; ++i) {
            const int gm = tileM + m0 + i;
            if (gm < KD)
                st4(&O[(size_t)gm * KD + gn],
                    make_float4(acc[i][0], acc[i][1], acc[i][2], acc[i][3]));
        }
    }
}

// ------- Kernel 2: batched single-reduction PCG, 8 systems/block, G in registers -------
// Change vs 192.9us base: G persisted in 100 VGPRs/thread (loaded ONCE; was 100 L2 loads
// per thread PER ITERATION = 1.15 GB L2 traffic), and 8 systems/block -> 200 blocks
// (one pass at 1 block/CU; 4-sys G-in-reg would need 2 passes). __launch_bounds__(512,2)
// sets VGPR budget 256 (2 waves/SIMD) to avoid the 128-VGPR spill cliff (R14/R16/R17:
// the default budget targets 4 waves/EU). Proven sub-patterns kept: all-lane P load +
// COMPILE-TIME readlane indices (R9/R10/R18), exact single-reduction rz recurrence,
// 3 barriers/iter. All register arrays indexed only from fully-unrolled loops; the
// NITER loop is pinned rolled to keep the ~1.3K-inst body in icache.
__global__ __launch_bounds__(512, 2) void cg_kernel(
    const float* __restrict__ G, const float* __restrict__ R,
    const float* __restrict__ ex, const float* __restrict__ ey,
    float* __restrict__ out)
{
    __shared__ __align__(16) float P[1664];            // p[c][s]=P[c*8+s], c<200,s<8 (+pad)
    __shared__ __align__(16) float PART[2][8][KD * 4]; // [syshalf][w][row*4+s'], 51.2 KB
    __shared__ __align__(16) float WP[8][32];          // [w][sys*4 + {pq,S2,S3,pad}]
    __shared__ float red8[8];

    const int tid = threadIdx.x;
    const int w = tid >> 6, l = tid & 63;
    const int blk = blockIdx.x;
    const int b = blk / 25;                // 25 blocks per batch
    const int i0 = (blk - b * 25) * 8;
    const int bK = b * KD;
    const float* __restrict__ Gb = G + (size_t)b * KD * KD;

    const bool mact = (l < 50);
    const int gcol = mact ? l : 49;        // lanes 50..63 duplicate row-group 49 (discarded)
    const int c0 = 25 * w;                 // this wave's 25 matvec columns

    // ---- G -> registers, ONCE (iteration-invariant addresses). g[c][j] = G[c0+c][l+50j].
    // Issued first so the 100 loads' latency hides under scale/state init below.
    float g[25][4];
    {
        const float* __restrict__ gld = Gb + (size_t)c0 * KD + gcol;
        #pragma unroll
        for (int c = 0; c < 25; ++c) {
            g[c][0] = gld[0];
            g[c][1] = gld[50];
            g[c][2] = gld[100];
            g[c][3] = gld[150];
            gld += KD;
        }
    }

    // ---- scale = max(ex[b,:], ey[b,:]) ----
    float mxv = 0.f;
    if (tid < KD) mxv = fmaxf(ex[bK + tid], ey[bK + tid]);
    #pragma unroll
    for (int off = 32; off > 0; off >>= 1)
        mxv = fmaxf(mxv, __shfl_down(mxv, off, 64));
    if (l == 0) red8[w] = mxv;
    __syncthreads();
    float scale = red8[0];
    #pragma unroll
    for (int wv = 1; wv < 8; ++wv) scale = fmaxf(scale, red8[wv]);
    const float inv_scale = 1.0f / scale;

    // ---- state init: thread (r=tid>>1, sq=tid&1) owns systems sq*4..sq*4+3 ----
    const bool stid = tid < 400;
    const int r = tid >> 1, sq = tid & 1;
    float lam[4], dinv[4], rr[4], xx[4], pp[4], rz4[4];
    if (stid) {
        const float exj = ex[bK + r] * inv_scale;
        const float e1 = sqrtf(exj);
        const float gdiag = Gb[(size_t)r * KD + r];
        const float* __restrict__ Rb = R + (size_t)(bK + i0 + sq * 4) * KD + r;
        #pragma unroll
        for (int j = 0; j < 4; ++j) {
            const float eyi = ey[bK + i0 + sq * 4 + j] * inv_scale;
            const float e2 = sqrtf(eyi);
            const float dn = exj + eyi;
            const float re = e2 - e1;
            lam[j] = LMB * ((re * re + 1.f) / (dn * dn));
            dinv[j] = 1.f / (gdiag + lam[j]);
            rr[j] = Rb[(size_t)j * KD];
            pp[j] = rr[j] * dinv[j];      // p0 = z0
            xx[j] = 0.f;
        }
        st4(&P[r * 8 + sq * 4], make_float4(pp[0], pp[1], pp[2], pp[3]));
    }
    // rz0 partials (WP slot 0 of each system)
    {
        float vg[4];
        #pragma unroll
        for (int j = 0; j < 4; ++j) vg[j] = stid ? rr[j] * pp[j] : 0.f;
        #pragma unroll
        for (int off = 2; off < 64; off <<= 1)
            #pragma unroll
            for (int j = 0; j < 4; ++j) vg[j] += __shfl_xor(vg[j], off, 64);
        if (l < 2) {
            #pragma unroll
            for (int j = 0; j < 4; ++j) WP[w][(l * 4 + j) * 4] = vg[j];
        }
    }
    __syncthreads();                       // P + rz0 partials ready
    if (stid) {
        #pragma unroll
        for (int j = 0; j < 4; ++j) {
            float s = 0.f;
            #pragma unroll
            for (int w8 = 0; w8 < 8; ++w8) s += WP[w8][(sq * 4 + j) * 4];
            rz4[j] = s;
        }
    }

    // ============ single-reduction PCG main loop (3 barriers/iter) ============
    #pragma unroll 1
    for (int k = 0; k < NITER; ++k) {
        __syncthreads();                   // B1: P stable, WP consumed

        // ---- matvec: pure register FMA + readlane broadcast (zero global traffic) ----
        float acc[4][8];
        #pragma unroll
        for (int j = 0; j < 4; ++j)
            #pragma unroll
            for (int s = 0; s < 8; ++s) acc[j][s] = 0.f;

        // 4 independent ds_reads up front -> one LDS latency, not four.
        // ALL lanes load (readlane hazard R9/R10); all 64 lane values consumed now.
        const float pvs[4] = { P[(c0 + 0)  * 8 + l], P[(c0 + 8)  * 8 + l],
                               P[(c0 + 16) * 8 + l], P[(c0 + 24) * 8 + l] };
        #pragma unroll
        for (int ch = 0; ch < 3; ++ch) {
            #pragma unroll
            for (int dc = 0; dc < 8; ++dc) {
                #pragma unroll
                for (int s = 0; s < 8; ++s) {
                    const float ps = rdlane(pvs[ch], dc * 8 + s);  // literal lane idx
                    acc[0][s] = fmaf(g[ch * 8 + dc][0], ps, acc[0][s]);
                    acc[1][s] = fmaf(g[ch * 8 + dc][1], ps, acc[1][s]);
                    acc[2][s] = fmaf(g[ch * 8 + dc][2], ps, acc[2][s]);
                    acc[3][s] = fmaf(g[ch * 8 + dc][3], ps, acc[3][s]);
                }
            }
        }
        #pragma unroll
        for (int s = 0; s < 8; ++s) {      // trailing column c0+24
            const float ps = rdlane(pvs[3], s);
            acc[0][s] = fmaf(g[24][0], ps, acc[0][s]);
            acc[1][s] = fmaf(g[24][1], ps, acc[1][s]);
            acc[2][s] = fmaf(g[24][2], ps, acc[2][s]);
            acc[3][s] = fmaf(g[24][3], ps, acc[3][s]);
        }
        if (mact) {
            #pragma unroll
            for (int j = 0; j < 4; ++j) {  // split halves: st4 16B/lane contiguous, 0-conflict
                const int row4 = (50 * j + l) * 4;
                st4(&PART[0][w][row4], make_float4(acc[j][0], acc[j][1], acc[j][2], acc[j][3]));
                st4(&PART[1][w][row4], make_float4(acc[j][4], acc[j][5], acc[j][6], acc[j][7]));
            }
        }
        __syncthreads();                   // B2: PART ready

        // ---- combine q + ALL THREE dot partials (pq, S2, S3) in one phase ----
        float qq[4], vpq[4], vs2[4], vs3[4];
        if (stid) {
            float s0 = 0.f, s1 = 0.f, s2 = 0.f, s3 = 0.f;
            #pragma unroll
            for (int w8 = 0; w8 < 8; ++w8) {
                const float4 f = ld4(&PART[sq][w8][r * 4]);   // 2-way (lo/hi) = free
                s0 += f.x; s1 += f.y; s2 += f.z; s3 += f.w;
            }
            qq[0] = fmaf(lam[0], pp[0], s0);
            qq[1] = fmaf(lam[1], pp[1], s1);
            qq[2] = fmaf(lam[2], pp[2], s2);
            qq[3] = fmaf(lam[3], pp[3], s3);
            #pragma unroll
            for (int j = 0; j < 4; ++j) {
                vpq[j] = pp[j] * qq[j];
                vs2[j] = dinv[j] * rr[j] * qq[j];
                vs3[j] = dinv[j] * qq[j] * qq[j];
            }
        } else {
            #pragma unroll
            for (int j = 0; j < 4; ++j) { qq[j] = 0.f; vpq[j] = vs2[j] = vs3[j] = 0.f; }
        }
        #pragma unroll
        for (int off = 2; off < 64; off <<= 1) {
            #pragma unroll
            for (int j = 0; j < 4; ++j) {
                vpq[j] += __shfl_xor(vpq[j], off, 64);
                vs2[j] += __shfl_xor(vs2[j], off, 64);
                vs3[j] += __shfl_xor(vs3[j], off, 64);
            }
        }
        if (l < 2) {
            #pragma unroll
            for (int j = 0; j < 4; ++j)
                st4(&WP[w][(l * 4 + j) * 4],
                    make_float4(vpq[j], vs2[j], vs3[j], 0.f));
        }
        __syncthreads();                   // B3: dots ready (the ONLY reduction barrier)

        // ---- all-scalar alpha/beta + x, r, p updates ----
        if (stid) {
            #pragma unroll
            for (int j = 0; j < 4; ++j) {
                float pq = 0.f, S2 = 0.f, S3 = 0.f;
                #pragma unroll
                for (int w8 = 0; w8 < 8; ++w8) {
                    const float4 f = ld4(&WP[w8][(sq * 4 + j) * 4]);   // broadcast
                    pq += f.x; S2 += f.y; S3 += f.z;
                }
                const float alpha = rz4[j] / pq;
                // rz_new = rz - 2a*S2 + a^2*S3  (exact expansion of sum d*(r-aq)^2)
                const float rzn = fmaf(alpha * alpha, S3, fmaf(-2.f * alpha, S2, rz4[j]));
                const float beta = rzn / rz4[j];
                rz4[j] = rzn;
                xx[j] = fmaf(alpha, pp[j], xx[j]);
                rr[j] = fmaf(-alpha, qq[j], rr[j]);
                pp[j] = fmaf(beta, pp[j], rr[j] * dinv[j]);   // p = z + beta p
            }
            st4(&P[r * 8 + sq * 4], make_float4(pp[0], pp[1], pp[2], pp[3]));
        }
    }

    // ---- store x ----
    if (stid) {
        float* __restrict__ Ob = out + (size_t)(bK + i0 + sq * 4) * KD + r;
        #pragma unroll
        for (int j = 0; j < 4; ++j) Ob[(size_t)j * KD] = xx[j];
    }
}

extern "C" void kernel_launch(void* const* d_in, const int* in_sizes, int n_in,
                              void* d_out, int out_size, void* d_ws, size_t ws_size,
                              hipStream_t stream) {
    const float* A  = (const float*)d_in[0];
    const float* B  = (const float*)d_in[1];
    const float* ex = (const float*)d_in[2];
    const float* ey = (const float*)d_in[3];
    float* out = (float*)d_out;

    float* G = (float*)d_ws;
    float* R = G + 8 * KD * KD;

    dim3 grid1(7, 7, 16);
    gemm_gr_kernel<<<grid1, 128, 0, stream>>>(A, B, G, R);

    cg_kernel<<<200, 512, 0, stream>>>(G, R, ex, ey, out);
}

// Round 2
// 240.940 us; speedup vs baseline: 1.4282x; 1.4282x over previous
//
#include <hip/hip_runtime.h>
#include <math.h>

#define KD 200
#define CD 352
#define NITER 18
#define LMB 0.01f

__device__ __forceinline__ float4 ld4(const float* p) { return *(const float4*)p; }
__device__ __forceinline__ void st4(float* p, float4 v) { *(float4*)p = v; }
__device__ __forceinline__ float rdlane(float v, int lane) {
    return __int_as_float(__builtin_amdgcn_readlane(__float_as_int(v), lane));
}

// ---------------- Kernel 1: G = A A^T, R = B A^T (batched, 32x32 tiles) ----------------
// 784 blocks: ~3 blocks/CU so one block's barriers overlap another's compute.
// 2-wave blocks, 2x4 micro-tile, register prefetch of next k-chunk between barriers.
// (Unchanged from R1 — after the cg fix this becomes the top dispatch; profile it then.)
__global__ __launch_bounds__(128) void gemm_gr_kernel(
    const float* __restrict__ A, const float* __restrict__ B,
    float* __restrict__ G, float* __restrict__ R)
{
    __shared__ __align__(16) float Ms[16][36];   // [k][m], pad to 36 (2-way max on writes)
    __shared__ __align__(16) float Ns[16][36];   // [k][n]
    const int tid = threadIdx.x;
    const int z = blockIdx.z;
    const int b = z >> 1, which = z & 1;
    const float* __restrict__ Xb = (which ? B : A) + (size_t)b * KD * CD;
    const float* __restrict__ Ab = A + (size_t)b * KD * CD;
    float* __restrict__ O = (which ? R : G) + (size_t)b * KD * KD;
    const int tileM = blockIdx.y * 32;
    const int tileN = blockIdx.x * 32;

    const int lm = tid >> 2;             // 0..31 (row within tile)
    const int kq = (tid & 3) * 4;        // 0,4,8,12
    const int rowM = min(tileM + lm, KD - 1);
    const int rowN = min(tileN + lm, KD - 1);
    const float* __restrict__ Xrow = Xb + (size_t)rowM * CD;
    const float* __restrict__ Arow = Ab + (size_t)rowN * CD;

    const int ty = tid >> 3, tx = tid & 7;   // ty 0..15, tx 0..7
    const int m0 = ty * 2, n0 = tx * 4;

    float acc[2][4] = {};
    // prefetch chunk 0 into registers
    float4 vx = ld4(Xrow + kq);
    float4 va = ld4(Arow + kq);
    for (int kk = 0; kk < CD; kk += 16) {
        __syncthreads();                 // previous chunk's LDS reads done
        Ms[kq + 0][lm] = vx.x; Ms[kq + 1][lm] = vx.y;
        Ms[kq + 2][lm] = vx.z; Ms[kq + 3][lm] = vx.w;
        Ns[kq + 0][lm] = va.x; Ns[kq + 1][lm] = va.y;
        Ns[kq + 2][lm] = va.z; Ns[kq + 3][lm] = va.w;
        if (kk + 16 < CD) {              // issue next chunk's loads; latency hides under FMAs
            vx = ld4(Xrow + kk + 16 + kq);
            va = ld4(Arow + kk + 16 + kq);
        }
        __syncthreads();                 // LDS writes visible
        #pragma unroll
        for (int k = 0; k < 16; ++k) {
            const float2 am = *(const float2*)&Ms[k][m0];
            const float4 an = ld4(&Ns[k][n0]);
            acc[0][0] = fmaf(am.x, an.x, acc[0][0]);
            acc[0][1] = fmaf(am.x, an.y, acc[0][1]);
            acc[0][2] = fmaf(am.x, an.z, acc[0][2]);
            acc[0][3] = fmaf(am.x, an.w, acc[0][3]);
            acc[1][0] = fmaf(am.y, an.x, acc[1][0]);
            acc[1][1] = fmaf(am.y, an.y, acc[1][1]);
            acc[1][2] = fmaf(am.y, an.z, acc[1][2]);
            acc[1][3] = fmaf(am.y, an.w, acc[1][3]);
        }
    }
    const int gn = tileN + n0;
    if (gn < KD) {
        #pragma unroll
        for (int i = 0; i < 2; ++i) {
            const int gm = tileM + m0 + i;
            if (gm < KD)
                st4(&O[(size_t)gm * KD + gn],
                    make_float4(acc[i][0], acc[i][1], acc[i][2], acc[i][3]));
        }
    }
}

// ------- Kernel 2: batched single-reduction PCG, 8 systems/block, G in registers -------
// R1 POST-MORTEM: __launch_bounds__(512,2) produced a 128-VGPR cap (behaved as 2
// BLOCKS/CU = 4 waves/SIMD = 512/4 regs), spilling g[25][4] to scratch: FETCH_SIZE
// 468 MB, dur 277us. Fix: pin the budget with the explicit backend attributes —
// flat_work_group_size(512,512) + waves_per_eu(2,2). A 512-thread block is 8 waves =
// 2/SIMD (1 block/CU, the natural occupancy), so waves_per_eu=2 <=> VGPR cap 512/2=256,
// comfortably above the ~180 this kernel needs. Everything else identical to R1:
// G persisted in 100 VGPRs/thread (loaded ONCE; the 192.9us base re-read 1.15 GB from
// L2), 8 systems/block -> 200 blocks (one pass on 200 CUs). Proven sub-patterns kept:
// all-lane P load + COMPILE-TIME readlane indices (R9/R10/R18), exact single-reduction
// rz recurrence, 3 barriers/iter. All register arrays indexed only from fully-unrolled
// loops; NITER loop pinned rolled.
__global__ __attribute__((amdgpu_flat_work_group_size(512, 512), amdgpu_waves_per_eu(2, 2)))
void cg_kernel(
    const float* __restrict__ G, const float* __restrict__ R,
    const float* __restrict__ ex, const float* __restrict__ ey,
    float* __restrict__ out)
{
    __shared__ __align__(16) float P[1664];            // p[c][s]=P[c*8+s], c<200,s<8 (+pad)
    __shared__ __align__(16) float PART[2][8][KD * 4]; // [syshalf][w][row*4+s'], 51.2 KB
    __shared__ __align__(16) float WP[8][32];          // [w][sys*4 + {pq,S2,S3,pad}]
    __shared__ float red8[8];

    const int tid = threadIdx.x;
    const int w = tid >> 6, l = tid & 63;
    const int blk = blockIdx.x;
    const int b = blk / 25;                // 25 blocks per batch
    const int i0 = (blk - b * 25) * 8;
    const int bK = b * KD;
    const float* __restrict__ Gb = G + (size_t)b * KD * KD;

    const bool mact = (l < 50);
    const int gcol = mact ? l : 49;        // lanes 50..63 duplicate row-group 49 (discarded)
    const int c0 = 25 * w;                 // this wave's 25 matvec columns

    // ---- G -> registers, ONCE (iteration-invariant addresses). g[c][j] = G[c0+c][l+50j].
    // Issued first so the 100 loads' latency hides under scale/state init below.
    float g[25][4];
    {
        const float* __restrict__ gld = Gb + (size_t)c0 * KD + gcol;
        #pragma unroll
        for (int c = 0; c < 25; ++c) {
            g[c][0] = gld[0];
            g[c][1] = gld[50];
            g[c][2] = gld[100];
            g[c][3] = gld[150];
            gld += KD;
        }
    }

    // ---- scale = max(ex[b,:], ey[b,:]) ----
    float mxv = 0.f;
    if (tid < KD) mxv = fmaxf(ex[bK + tid], ey[bK + tid]);
    #pragma unroll
    for (int off = 32; off > 0; off >>= 1)
        mxv = fmaxf(mxv, __shfl_down(mxv, off, 64));
    if (l == 0) red8[w] = mxv;
    __syncthreads();
    float scale = red8[0];
    #pragma unroll
    for (int wv = 1; wv < 8; ++wv) scale = fmaxf(scale, red8[wv]);
    const float inv_scale = 1.0f / scale;

    // ---- state init: thread (r=tid>>1, sq=tid&1) owns systems sq*4..sq*4+3 ----
    const bool stid = tid < 400;
    const int r = tid >> 1, sq = tid & 1;
    float lam[4], dinv[4], rr[4], xx[4], pp[4], rz4[4];
    if (stid) {
        const float exj = ex[bK + r] * inv_scale;
        const float e1 = sqrtf(exj);
        const float gdiag = Gb[(size_t)r * KD + r];
        const float* __restrict__ Rb = R + (size_t)(bK + i0 + sq * 4) * KD + r;
        #pragma unroll
        for (int j = 0; j < 4; ++j) {
            const float eyi = ey[bK + i0 + sq * 4 + j] * inv_scale;
            const float e2 = sqrtf(eyi);
            const float dn = exj + eyi;
            const float re = e2 - e1;
            lam[j] = LMB * ((re * re + 1.f) / (dn * dn));
            dinv[j] = 1.f / (gdiag + lam[j]);
            rr[j] = Rb[(size_t)j * KD];
            pp[j] = rr[j] * dinv[j];      // p0 = z0
            xx[j] = 0.f;
        }
        st4(&P[r * 8 + sq * 4], make_float4(pp[0], pp[1], pp[2], pp[3]));
    }
    // rz0 partials (WP slot 0 of each system)
    {
        float vg[4];
        #pragma unroll
        for (int j = 0; j < 4; ++j) vg[j] = stid ? rr[j] * pp[j] : 0.f;
        #pragma unroll
        for (int off = 2; off < 64; off <<= 1)
            #pragma unroll
            for (int j = 0; j < 4; ++j) vg[j] += __shfl_xor(vg[j], off, 64);
        if (l < 2) {
            #pragma unroll
            for (int j = 0; j < 4; ++j) WP[w][(l * 4 + j) * 4] = vg[j];
        }
    }
    __syncthreads();                       // P + rz0 partials ready
    if (stid) {
        #pragma unroll
        for (int j = 0; j < 4; ++j) {
            float s = 0.f;
            #pragma unroll
            for (int w8 = 0; w8 < 8; ++w8) s += WP[w8][(sq * 4 + j) * 4];
            rz4[j] = s;
        }
    }

    // ============ single-reduction PCG main loop (3 barriers/iter) ============
    #pragma unroll 1
    for (int k = 0; k < NITER; ++k) {
        __syncthreads();                   // B1: P stable, WP consumed

        // ---- matvec: pure register FMA + readlane broadcast (zero global traffic) ----
        float acc[4][8];
        #pragma unroll
        for (int j = 0; j < 4; ++j)
            #pragma unroll
            for (int s = 0; s < 8; ++s) acc[j][s] = 0.f;

        // 4 independent ds_reads up front -> one LDS latency, not four.
        // ALL lanes load (readlane hazard R9/R10); all 64 lane values consumed now.
        const float pvs[4] = { P[(c0 + 0)  * 8 + l], P[(c0 + 8)  * 8 + l],
                               P[(c0 + 16) * 8 + l], P[(c0 + 24) * 8 + l] };
        #pragma unroll
        for (int ch = 0; ch < 3; ++ch) {
            #pragma unroll
            for (int dc = 0; dc < 8; ++dc) {
                #pragma unroll
                for (int s = 0; s < 8; ++s) {
                    const float ps = rdlane(pvs[ch], dc * 8 + s);  // literal lane idx
                    acc[0][s] = fmaf(g[ch * 8 + dc][0], ps, acc[0][s]);
                    acc[1][s] = fmaf(g[ch * 8 + dc][1], ps, acc[1][s]);
                    acc[2][s] = fmaf(g[ch * 8 + dc][2], ps, acc[2][s]);
                    acc[3][s] = fmaf(g[ch * 8 + dc][3], ps, acc[3][s]);
                }
            }
        }
        #pragma unroll
        for (int s = 0; s < 8; ++s) {      // trailing column c0+24
            const float ps = rdlane(pvs[3], s);
            acc[0][s] = fmaf(g[24][0], ps, acc[0][s]);
            acc[1][s] = fmaf(g[24][1], ps, acc[1][s]);
            acc[2][s] = fmaf(g[24][2], ps, acc[2][s]);
            acc[3][s] = fmaf(g[24][3], ps, acc[3][s]);
        }
        if (mact) {
            #pragma unroll
            for (int j = 0; j < 4; ++j) {  // split halves: st4 16B/lane contiguous, 0-conflict
                const int row4 = (50 * j + l) * 4;
                st4(&PART[0][w][row4], make_float4(acc[j][0], acc[j][1], acc[j][2], acc[j][3]));
                st4(&PART[1][w][row4], make_float4(acc[j][4], acc[j][5], acc[j][6], acc[j][7]));
            }
        }
        __syncthreads();                   // B2: PART ready

        // ---- combine q + ALL THREE dot partials (pq, S2, S3) in one phase ----
        float qq[4], vpq[4], vs2[4], vs3[4];
        if (stid) {
            float s0 = 0.f, s1 = 0.f, s2 = 0.f, s3 = 0.f;
            #pragma unroll
            for (int w8 = 0; w8 < 8; ++w8) {
                const float4 f = ld4(&PART[sq][w8][r * 4]);   // 2-way (lo/hi) = free
                s0 += f.x; s1 += f.y; s2 += f.z; s3 += f.w;
            }
            qq[0] = fmaf(lam[0], pp[0], s0);
            qq[1] = fmaf(lam[1], pp[1], s1);
            qq[2] = fmaf(lam[2], pp[2], s2);
            qq[3] = fmaf(lam[3], pp[3], s3);
            #pragma unroll
            for (int j = 0; j < 4; ++j) {
                vpq[j] = pp[j] * qq[j];
                vs2[j] = dinv[j] * rr[j] * qq[j];
                vs3[j] = dinv[j] * qq[j] * qq[j];
            }
        } else {
            #pragma unroll
            for (int j = 0; j < 4; ++j) { qq[j] = 0.f; vpq[j] = vs2[j] = vs3[j] = 0.f; }
        }
        #pragma unroll
        for (int off = 2; off < 64; off <<= 1) {
            #pragma unroll
            for (int j = 0; j < 4; ++j) {
                vpq[j] += __shfl_xor(vpq[j], off, 64);
                vs2[j] += __shfl_xor(vs2[j], off, 64);
                vs3[j] += __shfl_xor(vs3[j], off, 64);
            }
        }
        if (l < 2) {
            #pragma unroll
            for (int j = 0; j < 4; ++j)
                st4(&WP[w][(l * 4 + j) * 4],
                    make_float4(vpq[j], vs2[j], vs3[j], 0.f));
        }
        __syncthreads();                   // B3: dots ready (the ONLY reduction barrier)

        // ---- all-scalar alpha/beta + x, r, p updates ----
        if (stid) {
            #pragma unroll
            for (int j = 0; j < 4; ++j) {
                float pq = 0.f, S2 = 0.f, S3 = 0.f;
                #pragma unroll
                for (int w8 = 0; w8 < 8; ++w8) {
                    const float4 f = ld4(&WP[w8][(sq * 4 + j) * 4]);   // broadcast
                    pq += f.x; S2 += f.y; S3 += f.z;
                }
                const float alpha = rz4[j] / pq;
                // rz_new = rz - 2a*S2 + a^2*S3  (exact expansion of sum d*(r-aq)^2)
                const float rzn = fmaf(alpha * alpha, S3, fmaf(-2.f * alpha, S2, rz4[j]));
                const float beta = rzn / rz4[j];
                rz4[j] = rzn;
                xx[j] = fmaf(alpha, pp[j], xx[j]);
                rr[j] = fmaf(-alpha, qq[j], rr[j]);
                pp[j] = fmaf(beta, pp[j], rr[j] * dinv[j]);   // p = z + beta p
            }
            st4(&P[r * 8 + sq * 4], make_float4(pp[0], pp[1], pp[2], pp[3]));
        }
    }

    // ---- store x ----
    if (stid) {
        float* __restrict__ Ob = out + (size_t)(bK + i0 + sq * 4) * KD + r;
        #pragma unroll
        for (int j = 0; j < 4; ++j) Ob[(size_t)j * KD] = xx[j];
    }
}

extern "C" void kernel_launch(void* const* d_in, const int* in_sizes, int n_in,
                              void* d_out, int out_size, void* d_ws, size_t ws_size,
                              hipStream_t stream) {
    const float* A  = (const float*)d_in[0];
    const float* B  = (const float*)d_in[1];
    const float* ex = (const float*)d_in[2];
    const float* ey = (const float*)d_in[3];
    float* out = (float*)d_out;

    float* G = (float*)d_ws;
    float* R = G + 8 * KD * KD;

    dim3 grid1(7, 7, 16);
    gemm_gr_kernel<<<grid1, 128, 0, stream>>>(A, B, G, R);

    cg_kernel<<<200, 512, 0, stream>>>(G, R, ex, ey, out);
}